// Round 1
// baseline (766.714 us; speedup 1.0000x reference)
//
#include <hip/hip_runtime.h>
#include <cmath>

typedef _Float16 f16;
typedef _Float16 f16x8 __attribute__((ext_vector_type(8)));
typedef float f32x4 __attribute__((ext_vector_type(4)));
typedef unsigned long long u64;

#define M_OUT 2049          // N//2 + 1
#define NDIM 4096
// reference: -2.0 * 3.14 / N computed in f64, rounded once to f32 (weak-scalar promotion)
#define CW ((float)(-2.0 * 3.14 / 4096.0))

// ws layout:
//   [0, 16384)            row means (4096 f32)
//   [16384, 16384+2049*8) argmax cells (u64, packed (amp2_bits<<32)|~col)
//   [40960, +4*TBL bytes) optional trig tables: ch, cl, sh, sl each 2112*4096 f16
static const size_t WS_MEAN  = 0;
static const size_t WS_CELLS = 16384;
static const size_t WS_TBL   = 40960;
static const size_t TBL_ELEMS = (size_t)2112 * 4096;

// ---------------- row means ----------------
__global__ void mean_kernel(const float* __restrict__ x, float* __restrict__ meanv) {
    const int row = blockIdx.x;
    const float4* xr = (const float4*)(x + (size_t)row * NDIM);
    float s = 0.f;
    for (int i = threadIdx.x; i < NDIM / 4; i += 256) {
        float4 v = xr[i];
        s += (v.x + v.y) + (v.z + v.w);
    }
    for (int off = 32; off; off >>= 1) s += __shfl_down(s, off);
    __shared__ float ps[4];
    if ((threadIdx.x & 63) == 0) ps[threadIdx.x >> 6] = s;
    __syncthreads();
    if (threadIdx.x == 0) {
        float t = (ps[0] + ps[1]) + (ps[2] + ps[3]);
        meanv[row] = t * (1.0f / 4096.0f);   // /4096 exact (pow2)
    }
}

// ---------------- init argmax cells ----------------
__global__ void init_cells(u64* __restrict__ cells) {
    int i = blockIdx.x * 256 + threadIdx.x;
    if (i < M_OUT) cells[i] = 0ull;
}

// ---------------- optional: precompute split trig tables ----------------
__global__ void fill_tables(f16* __restrict__ tbl) {
    long long g = (long long)blockIdx.x * 256 + threadIdx.x;   // one thread per 8 elems
    if (g >= (long long)(2112 * 512)) return;
    int m  = (int)(g >> 9);
    int kq = ((int)g & 511) * 8;
    bool valid = (m < M_OUT);
    f16x8 chv, clv, shv, slv;
    for (int j = 0; j < 8; ++j) {
        float c = 0.f, s = 0.f;
        if (valid) {
            int kk = kq + j;
            float ang = CW * (float)(m * kk);   // m*kk < 2^24 -> exact, matches reference
            sincosf(ang, &s, &c);
        }
        f16 ch = (f16)c; f16 cl = (f16)((c - (float)ch) * 64.0f);
        f16 sh = (f16)s; f16 sl = (f16)((s - (float)sh) * 64.0f);
        chv[j] = ch; clv[j] = cl; shv[j] = sh; slv[j] = sl;
    }
    size_t idx = (size_t)m * NDIM + kq;
    *(f16x8*)(tbl + idx)                 = chv;
    *(f16x8*)(tbl + TBL_ELEMS + idx)     = clv;
    *(f16x8*)(tbl + 2 * TBL_ELEMS + idx) = shv;
    *(f16x8*)(tbl + 3 * TBL_ELEMS + idx) = slv;
}

// ---------------- fused split-f16 DFT GEMM + argmax ----------------
// Tile: BM=64 (dft rows) x BN=128 (signal cols) x BK=32. 256 threads = 4 waves (2x2),
// each wave: 32x64 = 2x4 MFMA 16x16x32 tiles, 4 accumulators per tile
// (C_hi, C_mid, S_hi, S_mid; mid terms carry the 2^6 lo-scale).
__global__ __launch_bounds__(256, 2) void dft_gemm(
    const float* __restrict__ x, const float* __restrict__ meanv,
    const f16* __restrict__ tbl, int useTbl,
    u64* __restrict__ cells)
{
    __shared__ alignas(16) f16 Ach[64][32];
    __shared__ alignas(16) f16 Acl[64][32];
    __shared__ alignas(16) f16 Ash[64][32];
    __shared__ alignas(16) f16 Asl[64][32];
    __shared__ alignas(16) f16 Xh[128][32];   // transposed: [n][k]
    __shared__ alignas(16) f16 Xl[128][32];

    const int t = threadIdx.x;
    const int n0      = blockIdx.x * 128;
    const int rowBase = blockIdx.y * 64;

    // staging indices
    const int am  = t >> 2;            // 0..63   A row within tile
    const int akq = (t & 3) * 8;       // 0,8,16,24
    const int xn  = t & 127;           // 0..127  X column
    const int xkh = (t >> 7) * 16;     // 0,16

    const int lane = t & 63;
    const int w  = t >> 6;
    const int wm = w >> 1, wn = w & 1;
    const int q  = lane >> 4, ln = lane & 15;

    f32x4 aC0[2][4], aC1[2][4], aS0[2][4], aS1[2][4];
    for (int i = 0; i < 2; ++i)
        for (int j = 0; j < 4; ++j) {
            aC0[i][j] = (f32x4){0.f, 0.f, 0.f, 0.f};
            aC1[i][j] = (f32x4){0.f, 0.f, 0.f, 0.f};
            aS0[i][j] = (f32x4){0.f, 0.f, 0.f, 0.f};
            aS1[i][j] = (f32x4){0.f, 0.f, 0.f, 0.f};
        }

    const int arow = rowBase + am;
    const bool avalid = (arow < M_OUT);

    for (int k0 = 0; k0 < NDIM; k0 += 32) {
        __syncthreads();
        // ---- stage A (trig, split into f16 hi/lo) ----
        if (useTbl) {
            size_t idx = (size_t)arow * NDIM + k0 + akq;
            f16x8 chv = *(const f16x8*)(tbl + idx);
            f16x8 clv = *(const f16x8*)(tbl + TBL_ELEMS + idx);
            f16x8 shv = *(const f16x8*)(tbl + 2 * TBL_ELEMS + idx);
            f16x8 slv = *(const f16x8*)(tbl + 3 * TBL_ELEMS + idx);
            *(f16x8*)&Ach[am][akq] = chv;
            *(f16x8*)&Acl[am][akq] = clv;
            *(f16x8*)&Ash[am][akq] = shv;
            *(f16x8*)&Asl[am][akq] = slv;
        } else {
            f16x8 chv, clv, shv, slv;
            for (int j = 0; j < 8; ++j) {
                float c = 0.f, s = 0.f;
                if (avalid) {
                    int kk = k0 + akq + j;
                    float ang = CW * (float)(arow * kk);
                    sincosf(ang, &s, &c);
                }
                f16 ch = (f16)c; f16 cl = (f16)((c - (float)ch) * 64.0f);
                f16 sh = (f16)s; f16 sl = (f16)((s - (float)sh) * 64.0f);
                chv[j] = ch; clv[j] = cl; shv[j] = sh; slv[j] = sl;
            }
            *(f16x8*)&Ach[am][akq] = chv;
            *(f16x8*)&Acl[am][akq] = clv;
            *(f16x8*)&Ash[am][akq] = shv;
            *(f16x8*)&Asl[am][akq] = slv;
        }
        // ---- stage X (load, mean-subtract, split, transpose into LDS) ----
        {
            const float* xp = x + (size_t)(k0 + xkh) * NDIM + n0 + xn;
            f16x8 h0, h1, l0, l1;
            for (int r = 0; r < 16; ++r) {
                float v = xp[(size_t)r * NDIM] - meanv[k0 + xkh + r];
                f16 hi = (f16)v;
                f16 lo = (f16)((v - (float)hi) * 64.0f);
                if (r < 8) { h0[r] = hi; l0[r] = lo; }
                else       { h1[r - 8] = hi; l1[r - 8] = lo; }
            }
            *(f16x8*)&Xh[xn][xkh]     = h0;
            *(f16x8*)&Xh[xn][xkh + 8] = h1;
            *(f16x8*)&Xl[xn][xkh]     = l0;
            *(f16x8*)&Xl[xn][xkh + 8] = l1;
        }
        __syncthreads();
        // ---- fragments + MFMA ----
        f16x8 fch[2], fcl[2], fsh[2], fsl[2], bh[4], bl[4];
        for (int tm = 0; tm < 2; ++tm) {
            int ml = wm * 32 + tm * 16 + ln;
            fch[tm] = *(const f16x8*)&Ach[ml][q * 8];
            fcl[tm] = *(const f16x8*)&Acl[ml][q * 8];
            fsh[tm] = *(const f16x8*)&Ash[ml][q * 8];
            fsl[tm] = *(const f16x8*)&Asl[ml][q * 8];
        }
        for (int tn = 0; tn < 4; ++tn) {
            int nl = wn * 64 + tn * 16 + ln;
            bh[tn] = *(const f16x8*)&Xh[nl][q * 8];
            bl[tn] = *(const f16x8*)&Xl[nl][q * 8];
        }
        for (int tm = 0; tm < 2; ++tm)
            for (int tn = 0; tn < 4; ++tn) {
                aC0[tm][tn] = __builtin_amdgcn_mfma_f32_16x16x32_f16(fch[tm], bh[tn], aC0[tm][tn], 0, 0, 0);
                aC1[tm][tn] = __builtin_amdgcn_mfma_f32_16x16x32_f16(fch[tm], bl[tn], aC1[tm][tn], 0, 0, 0);
                aC1[tm][tn] = __builtin_amdgcn_mfma_f32_16x16x32_f16(fcl[tm], bh[tn], aC1[tm][tn], 0, 0, 0);
                aS0[tm][tn] = __builtin_amdgcn_mfma_f32_16x16x32_f16(fsh[tm], bh[tn], aS0[tm][tn], 0, 0, 0);
                aS1[tm][tn] = __builtin_amdgcn_mfma_f32_16x16x32_f16(fsh[tm], bl[tn], aS1[tm][tn], 0, 0, 0);
                aS1[tm][tn] = __builtin_amdgcn_mfma_f32_16x16x32_f16(fsl[tm], bh[tn], aS1[tm][tn], 0, 0, 0);
            }
    }

    // ---- epilogue: amp^2, per-row argmax, atomicMax into cells ----
    const float inv64 = 0.015625f;
    for (int tm = 0; tm < 2; ++tm) {
        for (int r = 0; r < 4; ++r) {
            u64 best = 0ull;
            for (int tn = 0; tn < 4; ++tn) {
                float C = aC0[tm][tn][r] + aC1[tm][tn][r] * inv64;
                float S = aS0[tm][tn][r] + aS1[tm][tn][r] * inv64;
                float a2 = C * C + S * S;
                int col = n0 + wn * 64 + tn * 16 + ln;
                u64 key = ((u64)__float_as_uint(a2) << 32) | (unsigned)(~col);
                if (key > best) best = key;
            }
            // reduce over the 16 lanes of this q-group (cols)
            for (int off = 1; off < 16; off <<= 1) {
                unsigned hi = (unsigned)(best >> 32), lo = (unsigned)best;
                unsigned ho = __shfl_xor(hi, off);
                unsigned lo2 = __shfl_xor(lo, off);
                u64 o = ((u64)ho << 32) | lo2;
                if (o > best) best = o;
            }
            if (ln == 0) {
                int grow = rowBase + wm * 32 + tm * 16 + q * 4 + r;
                if (grow < M_OUT) atomicMax(cells + grow, best);
            }
        }
    }
}

// ---------------- cells -> output ----------------
__global__ void out_kernel(const u64* __restrict__ cells, float* __restrict__ out) {
    int i = blockIdx.x * 256 + threadIdx.x;
    if (i < M_OUT) {
        unsigned col = ~(unsigned)(cells[i] & 0xFFFFFFFFull);
        float freq = (float)col / (4096.0f / 30.0f);   // matches reference f32 ops
        out[i] = freq * 60.0f;
    }
}

extern "C" void kernel_launch(void* const* d_in, const int* in_sizes, int n_in,
                              void* d_out, int out_size, void* d_ws, size_t ws_size,
                              hipStream_t stream) {
    const float* x = (const float*)d_in[0];
    char* ws = (char*)d_ws;
    float* meanv = (float*)(ws + WS_MEAN);
    u64*   cells = (u64*)(ws + WS_CELLS);
    f16*   tbl   = (f16*)(ws + WS_TBL);
    float* out   = (float*)d_out;

    const bool useTbl = (ws_size >= WS_TBL + 4 * TBL_ELEMS * sizeof(f16));

    hipLaunchKernelGGL(init_cells, dim3((M_OUT + 255) / 256), dim3(256), 0, stream, cells);
    hipLaunchKernelGGL(mean_kernel, dim3(NDIM), dim3(256), 0, stream, x, meanv);
    if (useTbl)
        hipLaunchKernelGGL(fill_tables, dim3(4224), dim3(256), 0, stream, tbl);
    hipLaunchKernelGGL(dft_gemm, dim3(32, 33), dim3(256), 0, stream,
                       x, meanv, tbl, (int)useTbl, cells);
    hipLaunchKernelGGL(out_kernel, dim3((M_OUT + 255) / 256), dim3(256), 0, stream, cells, out);
}

// Round 2
// 563.475 us; speedup vs baseline: 1.3607x; 1.3607x over previous
//
#include <hip/hip_runtime.h>
#include <cmath>

typedef _Float16 f16;
typedef _Float16 f16x8 __attribute__((ext_vector_type(8)));
typedef float f32x4 __attribute__((ext_vector_type(4)));
typedef unsigned long long u64;

#define M_OUT 2049          // N//2 + 1
#define NDIM 4096
#define MPAD 2112           // 2049 padded to 64-multiple (33 tiles)
// reference: -2.0 * 3.14 / N computed in f64, rounded once to f32
#define CW ((float)(-2.0 * 3.14 / 4096.0))

// ws layout:
//   [0, 16384)             row means (4096 f32)
//   [16384, 16384+2049*8)  argmax cells (u64, packed (amp2_bits<<32)|~col)
//   [40960, ...)           tables (layout depends on path)
// FULL path (chunk-major, for global_load_lds + conflict-free ds_read):
//   A tables: Ach,Acl,Ash,Asl each [512][2112][8] f16   (4 x 17.3 MB)
//   X tables: Xh,Xl           each [512][4096][8] f16   (2 x 33.6 MB)
// MID path (row-major as in R1): Ach,Acl,Ash,Asl each [2112][4096] f16
static const size_t WS_MEAN  = 0;
static const size_t WS_CELLS = 16384;
static const size_t WS_TBL   = 40960;
static const size_t A_ELEMS  = (size_t)MPAD * NDIM;        // 8650752
static const size_t X_ELEMS  = (size_t)NDIM * NDIM;        // 16777216
static const size_t WS_XTBL  = WS_TBL + 4 * A_ELEMS * sizeof(f16);   // 69246976
static const size_t WS_FULL_END = WS_XTBL + 2 * X_ELEMS * sizeof(f16); // 136355840
static const size_t WS_MID_END  = WS_TBL + 4 * A_ELEMS * sizeof(f16);

#define AS1 __attribute__((address_space(1)))
#define AS3 __attribute__((address_space(3)))
__device__ __forceinline__ void async_copy16(const void* gsrc, void* ldst) {
    __builtin_amdgcn_global_load_lds((const AS1 unsigned int*)gsrc,
                                     (AS3 unsigned int*)ldst, 16, 0, 0);
}

__device__ __forceinline__ void split_f16(float v, f16& hi, f16& lo) {
    hi = (f16)v;
    lo = (f16)((v - (float)hi) * 64.0f);
}

// ---------------- row means ----------------
__global__ void mean_kernel(const float* __restrict__ x, float* __restrict__ meanv) {
    const int row = blockIdx.x;
    const float4* xr = (const float4*)(x + (size_t)row * NDIM);
    float s = 0.f;
    for (int i = threadIdx.x; i < NDIM / 4; i += 256) {
        float4 v = xr[i];
        s += (v.x + v.y) + (v.z + v.w);
    }
    for (int off = 32; off; off >>= 1) s += __shfl_down(s, off);
    __shared__ float ps[4];
    if ((threadIdx.x & 63) == 0) ps[threadIdx.x >> 6] = s;
    __syncthreads();
    if (threadIdx.x == 0) {
        float t = (ps[0] + ps[1]) + (ps[2] + ps[3]);
        meanv[row] = t * (1.0f / 4096.0f);
    }
}

// ---------------- init argmax cells ----------------
__global__ void init_cells(u64* __restrict__ cells) {
    int i = blockIdx.x * 256 + threadIdx.x;
    if (i < M_OUT) cells[i] = 0ull;
}

// ================= FULL path: chunk-major tables =================
// A tables: elem index ((kc)*MPAD + m)*8 + j   (kc = k/8)
__global__ void fill_A_cm(f16* __restrict__ tbl) {
    const int c = blockIdx.x;                      // k-chunk 0..511
    const int m = blockIdx.y * 256 + threadIdx.x;  // 0..2303
    if (m >= MPAD) return;
    const bool valid = (m < M_OUT);
    f16x8 chv, clv, shv, slv;
    for (int j = 0; j < 8; ++j) {
        float cc = 0.f, ss = 0.f;
        if (valid) {
            int kk = c * 8 + j;
            float ang = CW * (float)(m * kk);      // m*kk < 2^24 -> exact
            sincosf(ang, &ss, &cc);
        }
        f16 h, l;
        split_f16(cc, h, l); chv[j] = h; clv[j] = l;
        split_f16(ss, h, l); shv[j] = h; slv[j] = l;
    }
    size_t idx = ((size_t)c * MPAD + m) * 8;
    *(f16x8*)(tbl + idx)                 = chv;
    *(f16x8*)(tbl + A_ELEMS + idx)       = clv;
    *(f16x8*)(tbl + 2 * A_ELEMS + idx)   = shv;
    *(f16x8*)(tbl + 3 * A_ELEMS + idx)   = slv;
}

// X tables: elem index ((kc)*NDIM + n)*8 + j ; value = x[k][n] - mean[k]
__global__ void fill_X_cm(const float* __restrict__ x, const float* __restrict__ meanv,
                          f16* __restrict__ xtbl) {
    const int c = blockIdx.x;                      // k-chunk 0..511
    const int n = blockIdx.y * 256 + threadIdx.x;  // 0..4095
    f16x8 hv, lv;
    for (int j = 0; j < 8; ++j) {
        int k = c * 8 + j;
        float v = x[(size_t)k * NDIM + n] - meanv[k];
        f16 h, l;
        split_f16(v, h, l);
        hv[j] = h; lv[j] = l;
    }
    size_t idx = ((size_t)c * NDIM + n) * 8;
    *(f16x8*)(xtbl + idx)           = hv;
    *(f16x8*)(xtbl + X_ELEMS + idx) = lv;
}

// Fused split-f16 DFT GEMM + argmax, chunk-major tables, global_load_lds staging.
// Tile: BM=64 x BN=128 x BK=32. 256 threads = 4 waves (2x2 of 32x64).
__global__ __launch_bounds__(256, 2) void dft_gemm_cm(
    const f16* __restrict__ atbl, const f16* __restrict__ xtbl,
    u64* __restrict__ cells)
{
    // [table][plane][row][8]
    __shared__ alignas(16) f16 sA[4][4][64][8];    // 16 KB
    __shared__ alignas(16) f16 sX[2][4][128][8];   // 16 KB

    const int t = threadIdx.x;
    const int n0      = blockIdx.x * 128;
    const int rowBase = blockIdx.y * 64;

    const int lane = t & 63;
    const int w  = t >> 6;
    const int wm = w >> 1, wn = w & 1;
    const int q  = lane >> 4, ln = lane & 15;

    f32x4 aC0[2][4], aC1[2][4], aS0[2][4], aS1[2][4];
    for (int i = 0; i < 2; ++i)
        for (int j = 0; j < 4; ++j) {
            aC0[i][j] = (f32x4){0.f, 0.f, 0.f, 0.f};
            aC1[i][j] = (f32x4){0.f, 0.f, 0.f, 0.f};
            aS0[i][j] = (f32x4){0.f, 0.f, 0.f, 0.f};
            aS1[i][j] = (f32x4){0.f, 0.f, 0.f, 0.f};
        }

    // per-wave staging base addresses (advance by stride each iter)
    // wave w stages A table w (4 planes) + Xh planes {w} halves, Xl likewise.
    const f16* aG = atbl + (size_t)w * A_ELEMS + ((size_t)0 * MPAD + rowBase + lane) * 8;
    // X ops per wave: o = w and o = w+4 over (plane = o>>1, half = o&1)
    const int xq0 = w >> 1, xh0 = w & 1;          // o = w
    const int xq1 = (w + 4) >> 1, xh1 = w & 1;    // o = w+4  (same parity)
    const f16* xhG0 = xtbl + ((size_t)xq0 * NDIM + n0 + xh0 * 64 + lane) * 8;
    const f16* xhG1 = xtbl + ((size_t)xq1 * NDIM + n0 + xh1 * 64 + lane) * 8;
    const f16* xlG0 = xhG0 + X_ELEMS * 8 / 8 * 8; // xtbl + X_ELEMS + ...
    const f16* xlG1 = xhG1 + X_ELEMS;
    // fix: xlG0 compute cleanly
    const f16* xlG0b = xtbl + X_ELEMS + ((size_t)xq0 * NDIM + n0 + xh0 * 64 + lane) * 8;

    for (int k0 = 0; k0 < NDIM; k0 += 32) {
        const int kc = k0 >> 3;   // base k-chunk, planes kc..kc+3
        __syncthreads();
        // ---- stage via global_load_lds (wave-uniform LDS base + lane*16) ----
        {
            const f16* g = aG + (size_t)kc * MPAD * 8;
            async_copy16(g,                         &sA[w][0][0][0]);
            async_copy16(g + (size_t)MPAD * 8,      &sA[w][1][0][0]);
            async_copy16(g + (size_t)2 * MPAD * 8,  &sA[w][2][0][0]);
            async_copy16(g + (size_t)3 * MPAD * 8,  &sA[w][3][0][0]);
        }
        {
            const size_t kadv = (size_t)kc * NDIM * 8;
            async_copy16(xhG0 + kadv,  &sX[0][xq0][xh0 * 64][0]);
            async_copy16(xhG1 + kadv,  &sX[0][xq1][xh1 * 64][0]);
            async_copy16(xlG0b + kadv, &sX[1][xq0][xh0 * 64][0]);
            async_copy16(xlG1 + kadv,  &sX[1][xq1][xh1 * 64][0]);
        }
        __syncthreads();
        // ---- fragments (conflict-free: lanes read sequential 16B) + MFMA ----
        f16x8 fch[2], fcl[2], fsh[2], fsl[2], bh[4], bl[4];
        for (int tm = 0; tm < 2; ++tm) {
            int ml = wm * 32 + tm * 16 + ln;
            fch[tm] = *(const f16x8*)&sA[0][q][ml][0];
            fcl[tm] = *(const f16x8*)&sA[1][q][ml][0];
            fsh[tm] = *(const f16x8*)&sA[2][q][ml][0];
            fsl[tm] = *(const f16x8*)&sA[3][q][ml][0];
        }
        for (int tn = 0; tn < 4; ++tn) {
            int nl = wn * 64 + tn * 16 + ln;
            bh[tn] = *(const f16x8*)&sX[0][q][nl][0];
            bl[tn] = *(const f16x8*)&sX[1][q][nl][0];
        }
        for (int tm = 0; tm < 2; ++tm)
            for (int tn = 0; tn < 4; ++tn) {
                aC0[tm][tn] = __builtin_amdgcn_mfma_f32_16x16x32_f16(fch[tm], bh[tn], aC0[tm][tn], 0, 0, 0);
                aC1[tm][tn] = __builtin_amdgcn_mfma_f32_16x16x32_f16(fch[tm], bl[tn], aC1[tm][tn], 0, 0, 0);
                aC1[tm][tn] = __builtin_amdgcn_mfma_f32_16x16x32_f16(fcl[tm], bh[tn], aC1[tm][tn], 0, 0, 0);
                aS0[tm][tn] = __builtin_amdgcn_mfma_f32_16x16x32_f16(fsh[tm], bh[tn], aS0[tm][tn], 0, 0, 0);
                aS1[tm][tn] = __builtin_amdgcn_mfma_f32_16x16x32_f16(fsh[tm], bl[tn], aS1[tm][tn], 0, 0, 0);
                aS1[tm][tn] = __builtin_amdgcn_mfma_f32_16x16x32_f16(fsl[tm], bh[tn], aS1[tm][tn], 0, 0, 0);
            }
    }

    // ---- epilogue: amp^2, per-row argmax, atomicMax into cells ----
    const float inv64 = 0.015625f;
    for (int tm = 0; tm < 2; ++tm) {
        for (int r = 0; r < 4; ++r) {
            u64 best = 0ull;
            for (int tn = 0; tn < 4; ++tn) {
                float C = aC0[tm][tn][r] + aC1[tm][tn][r] * inv64;
                float S = aS0[tm][tn][r] + aS1[tm][tn][r] * inv64;
                float a2 = C * C + S * S;
                int col = n0 + wn * 64 + tn * 16 + ln;
                u64 key = ((u64)__float_as_uint(a2) << 32) | (unsigned)(~col);
                if (key > best) best = key;
            }
            for (int off = 1; off < 16; off <<= 1) {
                unsigned hi = (unsigned)(best >> 32), lo = (unsigned)best;
                unsigned ho = __shfl_xor(hi, off);
                unsigned lo2 = __shfl_xor(lo, off);
                u64 o = ((u64)ho << 32) | lo2;
                if (o > best) best = o;
            }
            if (ln == 0) {
                int grow = rowBase + wm * 32 + tm * 16 + q * 4 + r;
                if (grow < M_OUT) atomicMax(cells + grow, best);
            }
        }
    }
}

// ================= MID/LOW path: R1 kernel with padded LDS =================
__global__ void fill_tables_rm(f16* __restrict__ tbl) {
    long long g = (long long)blockIdx.x * 256 + threadIdx.x;
    if (g >= (long long)(MPAD * 512)) return;
    int m  = (int)(g >> 9);
    int kq = ((int)g & 511) * 8;
    bool valid = (m < M_OUT);
    f16x8 chv, clv, shv, slv;
    for (int j = 0; j < 8; ++j) {
        float c = 0.f, s = 0.f;
        if (valid) {
            int kk = kq + j;
            float ang = CW * (float)(m * kk);
            sincosf(ang, &s, &c);
        }
        f16 h, l;
        split_f16(c, h, l); chv[j] = h; clv[j] = l;
        split_f16(s, h, l); shv[j] = h; slv[j] = l;
    }
    size_t idx = (size_t)m * NDIM + kq;
    *(f16x8*)(tbl + idx)               = chv;
    *(f16x8*)(tbl + A_ELEMS + idx)     = clv;
    *(f16x8*)(tbl + 2 * A_ELEMS + idx) = shv;
    *(f16x8*)(tbl + 3 * A_ELEMS + idx) = slv;
}

#define PK 40   // padded k-stride (80 B): bank groups (5*row+q)%8 cover all 8 -> 2-way (free)
__global__ __launch_bounds__(256, 2) void dft_gemm_fb(
    const float* __restrict__ x, const float* __restrict__ meanv,
    const f16* __restrict__ tbl, int useTbl,
    u64* __restrict__ cells)
{
    __shared__ alignas(16) f16 Ach[64][PK];
    __shared__ alignas(16) f16 Acl[64][PK];
    __shared__ alignas(16) f16 Ash[64][PK];
    __shared__ alignas(16) f16 Asl[64][PK];
    __shared__ alignas(16) f16 Xh[128][PK];
    __shared__ alignas(16) f16 Xl[128][PK];

    const int t = threadIdx.x;
    const int n0      = blockIdx.x * 128;
    const int rowBase = blockIdx.y * 64;

    const int am  = t >> 2;
    const int akq = (t & 3) * 8;
    const int xn  = t & 127;
    const int xkh = (t >> 7) * 16;

    const int lane = t & 63;
    const int w  = t >> 6;
    const int wm = w >> 1, wn = w & 1;
    const int q  = lane >> 4, ln = lane & 15;

    f32x4 aC0[2][4], aC1[2][4], aS0[2][4], aS1[2][4];
    for (int i = 0; i < 2; ++i)
        for (int j = 0; j < 4; ++j) {
            aC0[i][j] = (f32x4){0.f, 0.f, 0.f, 0.f};
            aC1[i][j] = (f32x4){0.f, 0.f, 0.f, 0.f};
            aS0[i][j] = (f32x4){0.f, 0.f, 0.f, 0.f};
            aS1[i][j] = (f32x4){0.f, 0.f, 0.f, 0.f};
        }

    const int arow = rowBase + am;
    const bool avalid = (arow < M_OUT);

    for (int k0 = 0; k0 < NDIM; k0 += 32) {
        __syncthreads();
        if (useTbl) {
            size_t idx = (size_t)arow * NDIM + k0 + akq;
            *(f16x8*)&Ach[am][akq] = *(const f16x8*)(tbl + idx);
            *(f16x8*)&Acl[am][akq] = *(const f16x8*)(tbl + A_ELEMS + idx);
            *(f16x8*)&Ash[am][akq] = *(const f16x8*)(tbl + 2 * A_ELEMS + idx);
            *(f16x8*)&Asl[am][akq] = *(const f16x8*)(tbl + 3 * A_ELEMS + idx);
        } else {
            f16x8 chv, clv, shv, slv;
            for (int j = 0; j < 8; ++j) {
                float c = 0.f, s = 0.f;
                if (avalid) {
                    int kk = k0 + akq + j;
                    float ang = CW * (float)(arow * kk);
                    sincosf(ang, &s, &c);
                }
                f16 h, l;
                split_f16(c, h, l); chv[j] = h; clv[j] = l;
                split_f16(s, h, l); shv[j] = h; slv[j] = l;
            }
            *(f16x8*)&Ach[am][akq] = chv;
            *(f16x8*)&Acl[am][akq] = clv;
            *(f16x8*)&Ash[am][akq] = shv;
            *(f16x8*)&Asl[am][akq] = slv;
        }
        {
            const float* xp = x + (size_t)(k0 + xkh) * NDIM + n0 + xn;
            f16x8 h0, h1, l0, l1;
            for (int r = 0; r < 16; ++r) {
                float v = xp[(size_t)r * NDIM] - meanv[k0 + xkh + r];
                f16 hi, lo;
                split_f16(v, hi, lo);
                if (r < 8) { h0[r] = hi; l0[r] = lo; }
                else       { h1[r - 8] = hi; l1[r - 8] = lo; }
            }
            *(f16x8*)&Xh[xn][xkh]     = h0;
            *(f16x8*)&Xh[xn][xkh + 8] = h1;
            *(f16x8*)&Xl[xn][xkh]     = l0;
            *(f16x8*)&Xl[xn][xkh + 8] = l1;
        }
        __syncthreads();
        f16x8 fch[2], fcl[2], fsh[2], fsl[2], bh[4], bl[4];
        for (int tm = 0; tm < 2; ++tm) {
            int ml = wm * 32 + tm * 16 + ln;
            fch[tm] = *(const f16x8*)&Ach[ml][q * 8];
            fcl[tm] = *(const f16x8*)&Acl[ml][q * 8];
            fsh[tm] = *(const f16x8*)&Ash[ml][q * 8];
            fsl[tm] = *(const f16x8*)&Asl[ml][q * 8];
        }
        for (int tn = 0; tn < 4; ++tn) {
            int nl = wn * 64 + tn * 16 + ln;
            bh[tn] = *(const f16x8*)&Xh[nl][q * 8];
            bl[tn] = *(const f16x8*)&Xl[nl][q * 8];
        }
        for (int tm = 0; tm < 2; ++tm)
            for (int tn = 0; tn < 4; ++tn) {
                aC0[tm][tn] = __builtin_amdgcn_mfma_f32_16x16x32_f16(fch[tm], bh[tn], aC0[tm][tn], 0, 0, 0);
                aC1[tm][tn] = __builtin_amdgcn_mfma_f32_16x16x32_f16(fch[tm], bl[tn], aC1[tm][tn], 0, 0, 0);
                aC1[tm][tn] = __builtin_amdgcn_mfma_f32_16x16x32_f16(fcl[tm], bh[tn], aC1[tm][tn], 0, 0, 0);
                aS0[tm][tn] = __builtin_amdgcn_mfma_f32_16x16x32_f16(fsh[tm], bh[tn], aS0[tm][tn], 0, 0, 0);
                aS1[tm][tn] = __builtin_amdgcn_mfma_f32_16x16x32_f16(fsh[tm], bl[tn], aS1[tm][tn], 0, 0, 0);
                aS1[tm][tn] = __builtin_amdgcn_mfma_f32_16x16x32_f16(fsl[tm], bh[tn], aS1[tm][tn], 0, 0, 0);
            }
    }

    const float inv64 = 0.015625f;
    for (int tm = 0; tm < 2; ++tm) {
        for (int r = 0; r < 4; ++r) {
            u64 best = 0ull;
            for (int tn = 0; tn < 4; ++tn) {
                float C = aC0[tm][tn][r] + aC1[tm][tn][r] * inv64;
                float S = aS0[tm][tn][r] + aS1[tm][tn][r] * inv64;
                float a2 = C * C + S * S;
                int col = n0 + wn * 64 + tn * 16 + ln;
                u64 key = ((u64)__float_as_uint(a2) << 32) | (unsigned)(~col);
                if (key > best) best = key;
            }
            for (int off = 1; off < 16; off <<= 1) {
                unsigned hi = (unsigned)(best >> 32), lo = (unsigned)best;
                unsigned ho = __shfl_xor(hi, off);
                unsigned lo2 = __shfl_xor(lo, off);
                u64 o = ((u64)ho << 32) | lo2;
                if (o > best) best = o;
            }
            if (ln == 0) {
                int grow = rowBase + wm * 32 + tm * 16 + q * 4 + r;
                if (grow < M_OUT) atomicMax(cells + grow, best);
            }
        }
    }
}

// ---------------- cells -> output ----------------
__global__ void out_kernel(const u64* __restrict__ cells, float* __restrict__ out) {
    int i = blockIdx.x * 256 + threadIdx.x;
    if (i < M_OUT) {
        unsigned col = ~(unsigned)(cells[i] & 0xFFFFFFFFull);
        float freq = (float)col / (4096.0f / 30.0f);
        out[i] = freq * 60.0f;
    }
}

extern "C" void kernel_launch(void* const* d_in, const int* in_sizes, int n_in,
                              void* d_out, int out_size, void* d_ws, size_t ws_size,
                              hipStream_t stream) {
    const float* x = (const float*)d_in[0];
    char* ws = (char*)d_ws;
    float* meanv = (float*)(ws + WS_MEAN);
    u64*   cells = (u64*)(ws + WS_CELLS);
    f16*   atbl  = (f16*)(ws + WS_TBL);
    f16*   xtbl  = (f16*)(ws + WS_XTBL);
    float* out   = (float*)d_out;

    hipLaunchKernelGGL(init_cells, dim3((M_OUT + 255) / 256), dim3(256), 0, stream, cells);
    hipLaunchKernelGGL(mean_kernel, dim3(NDIM), dim3(256), 0, stream, x, meanv);

    if (ws_size >= WS_FULL_END) {
        // FULL: chunk-major A + X tables, conflict-free global_load_lds GEMM
        hipLaunchKernelGGL(fill_A_cm, dim3(512, 9), dim3(256), 0, stream, atbl);
        hipLaunchKernelGGL(fill_X_cm, dim3(512, 16), dim3(256), 0, stream, x, meanv, xtbl);
        hipLaunchKernelGGL(dft_gemm_cm, dim3(32, 33), dim3(256), 0, stream, atbl, xtbl, cells);
    } else if (ws_size >= WS_MID_END) {
        hipLaunchKernelGGL(fill_tables_rm, dim3(4224), dim3(256), 0, stream, atbl);
        hipLaunchKernelGGL(dft_gemm_fb, dim3(32, 33), dim3(256), 0, stream,
                           x, meanv, atbl, 1, cells);
    } else {
        hipLaunchKernelGGL(dft_gemm_fb, dim3(32, 33), dim3(256), 0, stream,
                           x, meanv, atbl, 0, cells);
    }
    hipLaunchKernelGGL(out_kernel, dim3((M_OUT + 255) / 256), dim3(256), 0, stream, cells, out);
}